// Round 8
// baseline (312.124 us; speedup 1.0000x reference)
//
#include <hip/hip_runtime.h>

#define DEVI __device__ __forceinline__

typedef float  f32x4  __attribute__((ext_vector_type(4)));
typedef float  f32x16 __attribute__((ext_vector_type(16)));
typedef short  s16x8  __attribute__((ext_vector_type(8)));
typedef unsigned u32x4 __attribute__((ext_vector_type(4)));

DEVI void gload16(const void* g, void* l) {
  __builtin_amdgcn_global_load_lds(
      (const __attribute__((address_space(1))) void*)g,
      (__attribute__((address_space(3))) void*)l, 16, 0, 0);
}

DEVI ushort f2b(float f) {
  unsigned u = __builtin_bit_cast(unsigned, f);
  unsigned r = (u + 0x7fffu + ((u >> 16) & 1u)) >> 16;
  return (ushort)r;
}
DEVI unsigned cvtpk(float lo, float hi) {   // 2xf32 -> packed 2xbf16 (RNE)
  unsigned r;
  asm("v_cvt_pk_bf16_f32 %0, %1, %2" : "=v"(r) : "v"(lo), "v"(hi));
  return r;
}
DEVI float b2f(short s) {
  return __builtin_bit_cast(float, (unsigned)((ushort)s) << 16);
}
DEVI float max3(float a, float b, float c) { return fmaxf(fmaxf(a, b), c); }

DEVI f32x4 mfma16(s16x8 a, s16x8 b, f32x4 c) {
  return __builtin_amdgcn_mfma_f32_16x16x32_bf16(a, b, c, 0, 0, 0);
}
DEVI f32x16 mfma32(s16x8 a, s16x8 b, f32x16 c) {
  return __builtin_amdgcn_mfma_f32_32x32x16_bf16(a, b, c, 0, 0, 0);
}

// key permutation: swap bits 2<->3 (see k_flash comment).
DEVI int kperm(int r) {
  return (r & 0x13) | ((r & 4) << 1) | ((r & 8) >> 1);
}

// ---------------------------------------------------------------------------
// K0: prep wsrT only (the one tensor on gemm_sr's critical path).
//   wsrT [256][1024] <- w_sr [1024][256], bf16.
// ---------------------------------------------------------------------------
__global__ __launch_bounds__(256) void k_prep(
    const float* __restrict__ w_sr, ushort* __restrict__ wsrT)
{
  int o = blockIdx.x * 256 + threadIdx.x;
  int n = o >> 10, k = o & 1023;
  wsrT[o] = f2b(w_sr[k * 256 + n]);
}

// ---------------------------------------------------------------------------
// K1: SR GEMM + folded weight prep.
// Blocks [0,512):   XR[32768,256] = Xfold_f32[32768,1024] @ wsrT^T + b_sr.
//   BM=64 -> 512 blocks -> 2 blocks/CU (was 1: latency-bound).
// Blocks [512,2305): transpose wqkvT/woT + bqkv concat (consumed by LATER
//   kernels only -> no ordering hazard; hides under the GEMM).
// ---------------------------------------------------------------------------
__global__ __launch_bounds__(256, 2) void k_gemm_sr(
    const float* __restrict__ X, const ushort* __restrict__ WT,
    const float* __restrict__ bias, ushort* __restrict__ XR,
    const float* __restrict__ w_q, const float* __restrict__ b_q,
    const float* __restrict__ w_k, const float* __restrict__ b_k,
    const float* __restrict__ w_v, const float* __restrict__ b_v,
    const float* __restrict__ w_o,
    ushort* __restrict__ wqkvT, ushort* __restrict__ woT,
    float* __restrict__ bqkv)
{
  __shared__ float  As[64 * 32];     // 8 KB
  __shared__ ushort Bs[256 * 32];    // 16 KB
  const int tid = threadIdx.x;
  const int bx = blockIdx.x;

  if (bx >= 512) {                   // folded prep
    const int b = bx - 512;          // 0..1792
    if (b < 768) {                   // wqkvT [768][256]
      int o = b * 256 + tid;
      int n = o >> 8, k = o & 255;
      const float* w = (n < 256) ? w_q : (n < 512) ? w_k : w_v;
      wqkvT[o] = f2b(w[k * 256 + (n & 255)]);
    } else if (b < 1792) {           // woT [1024][256]
      int o = (b - 768) * 256 + tid;
      int n = o >> 8, k = o & 255;
      woT[o] = f2b(w_o[k * 1024 + n]);
    } else {
      bqkv[tid] = b_q[tid]; bqkv[256 + tid] = b_k[tid]; bqkv[512 + tid] = b_v[tid];
    }
    return;
  }

  const int l = tid & 63, w = tid >> 6;
  const int wr = w >> 1, wc = w & 1;
  const int g = l >> 4, lr = l & 15;
  const int xs = (bx & 7) * 64 + (bx >> 3);        // XCD-aware (512 = 8*64)
  const int tM = xs * 64;
  f32x4 acc[2][8] = {};

  for (int kt = 0; kt < 32; ++kt) {
    const int k0 = kt * 32;
#pragma unroll
    for (int j = 0; j < 2; ++j) {  // A: 8 KB fp32 (64 rows x 32 k)
      int chunk = j * 256 + tid;
      int row = chunk >> 3, kc = chunk & 7;
      gload16(X + (size_t)(tM + row) * 1024 + k0 + ((kc ^ (row & 7)) << 2),
              (char*)As + (j * 256 + w * 64) * 16);
    }
#pragma unroll
    for (int j = 0; j < 4; ++j) {  // B: 16 KB bf16 (256 rows, stride 1024)
      int chunk = j * 256 + tid;
      int row = chunk >> 2, kc = chunk & 3;
      gload16(WT + (size_t)row * 1024 + k0 + ((kc ^ (row & 3)) << 3),
              (char*)Bs + (j * 256 + w * 64) * 16);
    }
    __syncthreads();
    s16x8 bfr[8];
#pragma unroll
    for (int ni = 0; ni < 8; ++ni) {
      int col = wc * 128 + ni * 16 + lr;
      bfr[ni] = *(const s16x8*)&Bs[col * 32 + ((g ^ (col & 3)) << 3)];
    }
#pragma unroll
    for (int mi = 0; mi < 2; ++mi) {
      int row = wr * 32 + mi * 16 + lr;
      int c1 = (2 * g) ^ (row & 7);
      int c2 = (2 * g + 1) ^ (row & 7);
      f32x4 a0 = *(const f32x4*)&As[row * 32 + c1 * 4];
      f32x4 a1 = *(const f32x4*)&As[row * 32 + c2 * 4];
      s16x8 af = __builtin_bit_cast(s16x8,
          (u32x4){cvtpk(a0[0], a0[1]), cvtpk(a0[2], a0[3]),
                  cvtpk(a1[0], a1[1]), cvtpk(a1[2], a1[3])});
#pragma unroll
      for (int ni = 0; ni < 8; ++ni)
        acc[mi][ni] = mfma16(af, bfr[ni], acc[mi][ni]);
    }
    __syncthreads();
  }
#pragma unroll
  for (int ni = 0; ni < 8; ++ni) {
    const int col = wc * 128 + ni * 16 + lr;
    const float bv = bias[col];
#pragma unroll
    for (int mi = 0; mi < 2; ++mi) {
      const int r0 = tM + wr * 32 + mi * 16 + g * 4;
      f32x4 c = acc[mi][ni];
#pragma unroll
      for (int j = 0; j < 4; ++j)
        XR[(size_t)(r0 + j) * 256 + col] = f2b(c[j] + bv);
    }
  }
}

// ---------------------------------------------------------------------------
// K2: QKV GEMM.  C[32768,768] = XR_bf16[32768,256] @ wqkvT^T + bqkv.
// grid (256, 3): y-strip 0 -> Q rows, 1 -> K rows, 2 -> V transposed.
// ---------------------------------------------------------------------------
__global__ __launch_bounds__(256, 2) void k_gemm_qkv2(
    const ushort* __restrict__ XR, const ushort* __restrict__ WT,
    const float* __restrict__ bias,
    ushort* __restrict__ Qo, ushort* __restrict__ Ko, ushort* __restrict__ VTo)
{
  __shared__ ushort As[128 * 32];
  __shared__ ushort Bs[256 * 32];
  const int tid = threadIdx.x;
  const int l = tid & 63, w = tid >> 6;
  const int wr = w >> 1, wc = w & 1;
  const int g = l >> 4, lr = l & 15;
  const int bx = blockIdx.x;
  const int xs = (bx & 7) * 32 + (bx >> 3);
  const int tM = xs * 128, tN = blockIdx.y * 256;
  f32x4 acc[4][8] = {};

  for (int kt = 0; kt < 8; ++kt) {
    const int k0 = kt * 32;
#pragma unroll
    for (int j = 0; j < 2; ++j) {  // A: 8 KB bf16 (128 rows, stride 256)
      int chunk = j * 256 + tid;
      int row = chunk >> 2, kc = chunk & 3;
      gload16(XR + (size_t)(tM + row) * 256 + k0 + ((kc ^ (row & 3)) << 3),
              (char*)As + (j * 256 + w * 64) * 16);
    }
#pragma unroll
    for (int j = 0; j < 4; ++j) {  // B: 16 KB bf16 (256 rows, stride 256)
      int chunk = j * 256 + tid;
      int row = chunk >> 2, kc = chunk & 3;
      gload16(WT + (size_t)(tN + row) * 256 + k0 + ((kc ^ (row & 3)) << 3),
              (char*)Bs + (j * 256 + w * 64) * 16);
    }
    __syncthreads();
    s16x8 afr[4], bfr[8];
#pragma unroll
    for (int ni = 0; ni < 8; ++ni) {
      int col = wc * 128 + ni * 16 + lr;
      bfr[ni] = *(const s16x8*)&Bs[col * 32 + ((g ^ (col & 3)) << 3)];
    }
#pragma unroll
    for (int mi = 0; mi < 4; ++mi) {
      int row = wr * 64 + mi * 16 + lr;
      afr[mi] = *(const s16x8*)&As[row * 32 + ((g ^ (row & 3)) << 3)];
    }
#pragma unroll
    for (int mi = 0; mi < 4; ++mi)
#pragma unroll
      for (int ni = 0; ni < 8; ++ni)
        acc[mi][ni] = mfma16(afr[mi], bfr[ni], acc[mi][ni]);
    __syncthreads();
  }
  const int strip = blockIdx.y;
#pragma unroll
  for (int ni = 0; ni < 8; ++ni) {
    const int cc = wc * 128 + ni * 16 + lr;       // 0..255 within strip
    const float bv = bias[tN + cc];
#pragma unroll
    for (int mi = 0; mi < 4; ++mi) {
      const int r0 = tM + wr * 64 + mi * 16 + g * 4;
      f32x4 c = acc[mi][ni];
      if (strip < 2) {
        ushort* dst = strip ? Ko : Qo;
#pragma unroll
        for (int j = 0; j < 4; ++j)
          dst[(size_t)(r0 + j) * 256 + cc] = f2b(c[j] + bv);
      } else {
        const int n = r0 >> 12, lrr = r0 & 4095;
        ushort4 pv;
        pv.x = f2b(c[0] + bv); pv.y = f2b(c[1] + bv);
        pv.z = f2b(c[2] + bv); pv.w = f2b(c[3] + bv);
        *(ushort4*)&VTo[(size_t)n * 256 * 4096 + (size_t)cc * 4096 + lrr] = pv;
      }
    }
  }
}

// ---------------------------------------------------------------------------
// K3: flash attention.  4 waves x 32 q-rows, KBLK=32 double-buffered (64 KiB
// LDS -> 2 blocks/CU).  Conflict-free LDS layouts; K staged in kperm order so
// PV B-fragments are lane-local (zero shuffles).  Tile loop unrolled x2 with
// STATIC buffer index.  2-way KV split + combine fused into gemm_out.
// LDS map (bytes): K0@0  K1@16384  V0@32768  V1@49152.
// ---------------------------------------------------------------------------
#define KSC 0.0901687369f  /* log2(e)/sqrt(256) */

template<int NSPLIT>
__global__ __launch_bounds__(256, 2) void k_flash(
    const ushort* __restrict__ Qg, const ushort* __restrict__ Kg,
    const ushort* __restrict__ VTg, ushort* __restrict__ Po, float* __restrict__ MLo)
{
  __shared__ ushort SB[32768];
  const int tid = threadIdx.x;
  const int l = tid & 63, w = tid >> 6;
  const int by = blockIdx.x & 7;                       // batch -> XCD
  const int rest = blockIdx.x >> 3;
  const int split = (NSPLIT == 2) ? (rest & 1) : 0;
  const int qt = (NSPLIT == 2) ? (rest >> 1) : rest;
  const int NT = (NSPLIT == 2) ? 64 : 128;
  const int kv0 = split * 2048;
  const int q0 = qt * 128 + w * 32;
  const int cl = l & 31, h = l >> 5;
  const size_t qrow = (size_t)by * 4096 + q0 + cl;

  s16x8 qf[16];
#pragma unroll
  for (int s = 0; s < 16; ++s)
    qf[s] = *(const s16x8*)&Qg[qrow * 256 + s * 16 + h * 8];

  f32x16 ot[8] = {};
  float m_run = -1e30f, l_run = 0.0f;   // l_run is a per-half partial sum

  // loop-invariant per-thread LDS byte offsets
  const char* SBc = (const char*)SB;
  const int tbK = h * 512 + cl * 16;    // K: (2s+h)*512 + cl*16 - s part is imm
  const int tbV = h * 4096 + cl * 16;   // V: ks*8192 + h*4096 + mf*512 + cl*16

  // strength-reduced global staging pointers (j-dependence folds into imm)
  const ushort* kg = Kg + ((size_t)by * 4096 + kv0) * 256
                   + kperm(tid & 31) * 256 + (tid >> 5) * 8;   // +8192/tile
  const ushort* vg = VTg + (size_t)by * 256 * 4096 + kv0
                   + (size_t)tid * 4096;                       // +32/tile

  auto stageK = [&](const ushort* p, int buf) {
#pragma unroll
    for (int j = 0; j < 4; ++j)
      gload16(p + j * 64, (char*)SB + buf * 16384 + j * 4096 + w * 1024);
  };
  auto stageV = [&](const ushort* p, int buf) {
#pragma unroll
    for (int j = 0; j < 4; ++j)
      gload16(p + j * 8, (char*)SB + 32768 + buf * 16384 + j * 4096 + w * 1024);
  };

  stageK(kg, 0); stageV(vg, 0);
  __syncthreads();

#define FLASH_TILE(BUF)                                                        \
  {                                                                            \
    f32x16 sa = {};                                                            \
    __builtin_amdgcn_s_setprio(1);                                             \
    _Pragma("unroll")                                                          \
    for (int s = 0; s < 16; ++s) {                                             \
      s16x8 a = *(const s16x8*)(SBc + (BUF) * 16384 + s * 1024 + tbK);         \
      sa = mfma32(a, qf[s], sa);                                               \
    }                                                                          \
    __builtin_amdgcn_s_setprio(0);                                             \
    float t0 = max3(sa[0], sa[1], sa[2]);                                      \
    float t1 = max3(sa[3], sa[4], sa[5]);                                      \
    float t2 = max3(sa[6], sa[7], sa[8]);                                      \
    float t3 = max3(sa[9], sa[10], sa[11]);                                    \
    float t4 = max3(sa[12], sa[13], sa[14]);                                   \
    float pmax = fmaxf(max3(t0, t1, t2), max3(t3, t4, sa[15]));                \
    pmax = fmaxf(pmax, __shfl_xor(pmax, 32));                                  \
    if (!__all(pmax <= m_run + 120.0f)) {                                      \
      float m_new = fmaxf(m_run, pmax);                                        \
      float corr = exp2f((m_run - m_new) * KSC);                               \
      l_run *= corr;                                                           \
      _Pragma("unroll")                                                        \
      for (int mf = 0; mf < 8; ++mf)                                           \
        _Pragma("unroll")                                                      \
        for (int i = 0; i < 16; ++i) ot[mf][i] *= corr;                        \
      m_run = m_new;                                                           \
    }                                                                          \
    const float mK = m_run * KSC;                                              \
    unsigned pk[4][2];                                                         \
    float lp = 0.0f;                                                           \
    _Pragma("unroll")                                                          \
    for (int gq = 0; gq < 4; ++gq) {                                           \
      float p0 = exp2f(__builtin_fmaf(sa[4 * gq + 0], KSC, -mK));              \
      float p1 = exp2f(__builtin_fmaf(sa[4 * gq + 1], KSC, -mK));              \
      float p2 = exp2f(__builtin_fmaf(sa[4 * gq + 2], KSC, -mK));              \
      float p3 = exp2f(__builtin_fmaf(sa[4 * gq + 3], KSC, -mK));              \
      lp += (p0 + p1) + (p2 + p3);                                             \
      pk[gq][0] = cvtpk(p0, p1);                                               \
      pk[gq][1] = cvtpk(p2, p3);                                               \
    }                                                                          \
    l_run += lp;                                                               \
    _Pragma("unroll")                                                          \
    for (int ks = 0; ks < 2; ++ks) {                                           \
      const s16x8 pf = __builtin_bit_cast(s16x8,                               \
          (u32x4){pk[2 * ks][0], pk[2 * ks][1],                                \
                  pk[2 * ks + 1][0], pk[2 * ks + 1][1]});                      \
      __builtin_amdgcn_s_setprio(1);                                           \
      _Pragma("unroll")                                                        \
      for (int mf = 0; mf < 8; ++mf) {                                         \
        s16x8 va = *(const s16x8*)(SBc + 32768 + (BUF) * 16384 +               \
                                   ks * 8192 + mf * 512 + tbV);                \
        ot[mf] = mfma32(va, pf, ot[mf]);                                       \
      }                                                                        \
      __builtin_amdgcn_s_setprio(0);                                           \
    }                                                                          \
    __syncthreads();                                                           \
  }

  for (int t = 0; t < NT; t += 2) {
    if (t + 1 < NT) { stageK(kg + 8192, 1); stageV(vg + 32, 1); }
    FLASH_TILE(0)
    if (t + 2 < NT) { stageK(kg + 16384, 0); stageV(vg + 64, 0); }
    FLASH_TILE(1)
    kg += 16384; vg += 64;
  }
#undef FLASH_TILE

  const float l_tot = l_run + __shfl_xor(l_run, 32);
  const float rl = 1.0f / l_tot;
  const size_t orow = (size_t)split * 32768 + qrow;
#pragma unroll
  for (int mf = 0; mf < 8; ++mf)
#pragma unroll
    for (int c = 0; c < 4; ++c) {
      const int d0 = mf * 32 + 8 * c + 4 * h;
      uint2 pv;
      pv.x = cvtpk(ot[mf][4 * c + 0] * rl, ot[mf][4 * c + 1] * rl);
      pv.y = cvtpk(ot[mf][4 * c + 2] * rl, ot[mf][4 * c + 3] * rl);
      *(uint2*)&Po[orow * 256 + d0] = pv;
    }
  if (NSPLIT == 2 && h == 0) {
    float2 ml; ml.x = m_run; ml.y = l_tot;
    *(float2*)&MLo[orow * 2] = ml;
  }
}

// ---------------------------------------------------------------------------
// K4: out projection with fused split-combine.
// OUT_f32[32768,1024] = combine(P0,P1;ML)_bf16[32768,256] @ WOT^T + b_o.
// ---------------------------------------------------------------------------
template<int COMB>
__global__ __launch_bounds__(256, 2) void k_gemm_out(
    const ushort* __restrict__ P0, const float* __restrict__ ML,
    const ushort* __restrict__ WT,
    const float* __restrict__ bias, float* __restrict__ OUT)
{
  __shared__ ushort As[128 * 32];
  __shared__ ushort Bs[256 * 32];
  __shared__ float2 Wr[128];
  const int tid = threadIdx.x;
  const int l = tid & 63, w = tid >> 6;
  const int wr = w >> 1, wc = w & 1;
  const int g = l >> 4, lr = l & 15;
  const int tM = blockIdx.x * 128, tN = blockIdx.y * 256;
  f32x4 acc[4][8] = {};

  if (COMB) {
    if (tid < 128) {
      const int r = tM + tid;
      float2 ml0 = *(const float2*)&ML[(size_t)r * 2];
      float2 ml1 = *(const float2*)&ML[(size_t)(32768 + r) * 2];
      float m = fmaxf(ml0.x, ml1.x);
      float a0 = ml0.y * exp2f((ml0.x - m) * KSC);
      float a1 = ml1.y * exp2f((ml1.x - m) * KSC);
      float inv = 1.0f / (a0 + a1);
      float2 wv; wv.x = a0 * inv; wv.y = a1 * inv;
      Wr[tid] = wv;
    }
    __syncthreads();
  }

  for (int kt = 0; kt < 8; ++kt) {
    const int k0 = kt * 32;
    if (COMB) {
#pragma unroll
      for (int j = 0; j < 2; ++j) {  // A: merge both partials -> bf16 LDS
        int chunk = j * 256 + tid;
        int row = chunk >> 2, kc = chunk & 3;
        size_t src = (size_t)(tM + row) * 256 + k0 + ((kc ^ (row & 3)) << 3);
        s16x8 x0 = *(const s16x8*)&P0[src];
        s16x8 x1 = *(const s16x8*)&P0[src + (size_t)32768 * 256];
        float2 wv = Wr[row];
        u32x4 m;
#pragma unroll
        for (int p = 0; p < 4; ++p) {
          float lo = __builtin_fmaf(wv.y, b2f(x1[2 * p]),     wv.x * b2f(x0[2 * p]));
          float hi = __builtin_fmaf(wv.y, b2f(x1[2 * p + 1]), wv.x * b2f(x0[2 * p + 1]));
          m[p] = cvtpk(lo, hi);
        }
        *(s16x8*)((char*)As + chunk * 16) = __builtin_bit_cast(s16x8, m);
      }
    } else {
#pragma unroll
      for (int j = 0; j < 2; ++j) {  // A: 128x32 bf16 direct
        int chunk = j * 256 + tid;
        int row = chunk >> 2, kc = chunk & 3;
        gload16(P0 + (size_t)(tM + row) * 256 + k0 + ((kc ^ (row & 3)) << 3),
                (char*)As + (j * 256 + w * 64) * 16);
      }
    }
#pragma unroll
    for (int j = 0; j < 4; ++j) {  // B: 256x32 bf16
      int chunk = j * 256 + tid;
      int row = chunk >> 2, kc = chunk & 3;
      gload16(WT + (size_t)(tN + row) * 256 + k0 + ((kc ^ (row & 3)) << 3),
              (char*)Bs + (j * 256 + w * 64) * 16);
    }
    __syncthreads();
    s16x8 afr[4], bfr[8];
#pragma unroll
    for (int ni = 0; ni < 8; ++ni) {
      int col = wc * 128 + ni * 16 + lr;
      bfr[ni] = *(const s16x8*)&Bs[col * 32 + ((g ^ (col & 3)) << 3)];
    }
#pragma unroll
    for (int mi = 0; mi < 4; ++mi) {
      int row = wr * 64 + mi * 16 + lr;
      afr[mi] = *(const s16x8*)&As[row * 32 + ((g ^ (row & 3)) << 3)];
    }
#pragma unroll
    for (int mi = 0; mi < 4; ++mi)
#pragma unroll
      for (int ni = 0; ni < 8; ++ni)
        acc[mi][ni] = mfma16(afr[mi], bfr[ni], acc[mi][ni]);
    __syncthreads();
  }
#pragma unroll
  for (int ni = 0; ni < 8; ++ni) {
    const int col = tN + wc * 128 + ni * 16 + lr;
    const float bv = bias[col];
#pragma unroll
    for (int mi = 0; mi < 4; ++mi) {
      const int r0 = tM + wr * 64 + mi * 16 + g * 4;
      f32x4 c = acc[mi][ni];
#pragma unroll
      for (int j = 0; j < 4; ++j)
        OUT[(size_t)(r0 + j) * 1024 + col] = c[j] + bv;
    }
  }
}

// ---------------------------------------------------------------------------
extern "C" void kernel_launch(void* const* d_in, const int* in_sizes, int n_in,
                              void* d_out, int out_size, void* d_ws, size_t ws_size,
                              hipStream_t stream) {
  const float* x    = (const float*)d_in[0];
  const float* w_sr = (const float*)d_in[1];
  const float* b_sr = (const float*)d_in[2];
  const float* w_q  = (const float*)d_in[3];
  const float* b_q  = (const float*)d_in[4];
  const float* w_k  = (const float*)d_in[5];
  const float* b_k  = (const float*)d_in[6];
  const float* w_v  = (const float*)d_in[7];
  const float* b_v  = (const float*)d_in[8];
  const float* w_o  = (const float*)d_in[9];
  const float* b_o  = (const float*)d_in[10];
  float* out = (float*)d_out;

  char* ws = (char*)d_ws;
  const size_t MB = 1024 * 1024;
  const size_t KB = 1024;
  const bool split = ws_size >= 84 * MB;

  ushort* Q  = (ushort*)(ws);
  ushort* K  = (ushort*)(ws + 16 * MB);
  ushort* VT = (ushort*)(ws + 32 * MB);
  ushort* XR = (ushort*)(ws + 48 * MB);      // dead before flash writes P here
  ushort* P  = (ushort*)(ws + 48 * MB);      // [split0 | split1]
  float*  ML    = (float*) (ws + 80 * MB);
  char*   wbase = split ? (ws + 80 * MB + 512 * KB) : (ws + 64 * MB);
  ushort* WSRT  = (ushort*)(wbase);                  // 512 KB
  ushort* WQKVT = (ushort*)(wbase + 512 * KB);       // 384 KB
  ushort* WOT   = (ushort*)(wbase + 1024 * KB);      // 512 KB
  float*  BQKV  = (float*) (wbase + 1536 * KB);      // 3 KB

  k_prep<<<1024, 256, 0, stream>>>(w_sr, WSRT);
  k_gemm_sr<<<2305, 256, 0, stream>>>(x, WSRT, b_sr, XR,
                                      w_q, b_q, w_k, b_k, w_v, b_v, w_o,
                                      WQKVT, WOT, BQKV);
  k_gemm_qkv2<<<dim3(256, 3), 256, 0, stream>>>(XR, WQKVT, BQKV, Q, K, VT);
  if (split) {
    k_flash<2><<<512, 256, 0, stream>>>(Q, K, VT, P, ML);
    k_gemm_out<1><<<dim3(256, 4), 256, 0, stream>>>(P, ML, WOT, b_o, out);
  } else {
    k_flash<1><<<256, 256, 0, stream>>>(Q, K, VT, P, nullptr);
    k_gemm_out<0><<<dim3(256, 4), 256, 0, stream>>>(P, nullptr, WOT, b_o, out);
  }
}

// Round 9
// 311.123 us; speedup vs baseline: 1.0032x; 1.0032x over previous
//
#include <hip/hip_runtime.h>

#define DEVI __device__ __forceinline__

typedef float  f32x4  __attribute__((ext_vector_type(4)));
typedef float  f32x16 __attribute__((ext_vector_type(16)));
typedef short  s16x8  __attribute__((ext_vector_type(8)));
typedef unsigned u32x4 __attribute__((ext_vector_type(4)));

DEVI void gload16(const void* g, void* l) {
  __builtin_amdgcn_global_load_lds(
      (const __attribute__((address_space(1))) void*)g,
      (__attribute__((address_space(3))) void*)l, 16, 0, 0);
}

DEVI ushort f2b(float f) {
  unsigned u = __builtin_bit_cast(unsigned, f);
  unsigned r = (u + 0x7fffu + ((u >> 16) & 1u)) >> 16;
  return (ushort)r;
}
DEVI unsigned cvtpk(float lo, float hi) {   // 2xf32 -> packed 2xbf16 (RNE)
  unsigned r;
  asm("v_cvt_pk_bf16_f32 %0, %1, %2" : "=v"(r) : "v"(lo), "v"(hi));
  return r;
}
DEVI float b2f(short s) {
  return __builtin_bit_cast(float, (unsigned)((ushort)s) << 16);
}
DEVI float max3(float a, float b, float c) { return fmaxf(fmaxf(a, b), c); }

DEVI f32x4 mfma16(s16x8 a, s16x8 b, f32x4 c) {
  return __builtin_amdgcn_mfma_f32_16x16x32_bf16(a, b, c, 0, 0, 0);
}
DEVI f32x16 mfma32(s16x8 a, s16x8 b, f32x16 c) {
  return __builtin_amdgcn_mfma_f32_32x32x16_bf16(a, b, c, 0, 0, 0);
}

// key permutation: swap bits 2<->3 (see k_flash comment).
DEVI int kperm(int r) {
  return (r & 0x13) | ((r & 4) << 1) | ((r & 8) >> 1);
}

// ---------------------------------------------------------------------------
// K0: prep wsrT only (the one tensor on gemm_sr's critical path).
//   wsrT [256][1024] <- w_sr [1024][256], bf16.
// ---------------------------------------------------------------------------
__global__ __launch_bounds__(256) void k_prep(
    const float* __restrict__ w_sr, ushort* __restrict__ wsrT)
{
  int o = blockIdx.x * 256 + threadIdx.x;
  int n = o >> 10, k = o & 1023;
  wsrT[o] = f2b(w_sr[k * 256 + n]);
}

// ---------------------------------------------------------------------------
// K1: SR GEMM + folded weight prep.
// Blocks [0,256):   XR[32768,256] = Xfold_f32[32768,1024] @ wsrT^T + b_sr.
//   BM=128 (HBM-bound on X; BM=64 doubled WT restage for no gain - R8).
// Blocks [256,2049): transpose wqkvT/woT + bqkv concat (consumed by LATER
//   kernels only -> no ordering hazard; hides under the GEMM).
// ---------------------------------------------------------------------------
__global__ __launch_bounds__(256, 2) void k_gemm_sr(
    const float* __restrict__ X, const ushort* __restrict__ WT,
    const float* __restrict__ bias, ushort* __restrict__ XR,
    const float* __restrict__ w_q, const float* __restrict__ b_q,
    const float* __restrict__ w_k, const float* __restrict__ b_k,
    const float* __restrict__ w_v, const float* __restrict__ b_v,
    const float* __restrict__ w_o,
    ushort* __restrict__ wqkvT, ushort* __restrict__ woT,
    float* __restrict__ bqkv)
{
  __shared__ float  As[128 * 32];    // 16 KB
  __shared__ ushort Bs[256 * 32];    // 16 KB
  const int tid = threadIdx.x;
  const int bx = blockIdx.x;

  if (bx >= 256) {                   // folded prep
    const int b = bx - 256;          // 0..1792
    if (b < 768) {                   // wqkvT [768][256]
      int o = b * 256 + tid;
      int n = o >> 8, k = o & 255;
      const float* w = (n < 256) ? w_q : (n < 512) ? w_k : w_v;
      wqkvT[o] = f2b(w[k * 256 + (n & 255)]);
    } else if (b < 1792) {           // woT [1024][256]
      int o = (b - 768) * 256 + tid;
      int n = o >> 8, k = o & 255;
      woT[o] = f2b(w_o[k * 1024 + n]);
    } else {
      bqkv[tid] = b_q[tid]; bqkv[256 + tid] = b_k[tid]; bqkv[512 + tid] = b_v[tid];
    }
    return;
  }

  const int l = tid & 63, w = tid >> 6;
  const int wr = w >> 1, wc = w & 1;
  const int g = l >> 4, lr = l & 15;
  const int xs = (bx & 7) * 32 + (bx >> 3);        // XCD-aware (256 % 8 == 0)
  const int tM = xs * 128;
  f32x4 acc[4][8] = {};

  for (int kt = 0; kt < 32; ++kt) {
    const int k0 = kt * 32;
#pragma unroll
    for (int j = 0; j < 4; ++j) {  // A: 16 KB fp32
      int chunk = j * 256 + tid;
      int row = chunk >> 3, kc = chunk & 7;
      gload16(X + (size_t)(tM + row) * 1024 + k0 + ((kc ^ (row & 7)) << 2),
              (char*)As + (j * 256 + w * 64) * 16);
    }
#pragma unroll
    for (int j = 0; j < 4; ++j) {  // B: 16 KB bf16 (256 rows, stride 1024)
      int chunk = j * 256 + tid;
      int row = chunk >> 2, kc = chunk & 3;
      gload16(WT + (size_t)row * 1024 + k0 + ((kc ^ (row & 3)) << 3),
              (char*)Bs + (j * 256 + w * 64) * 16);
    }
    __syncthreads();
    s16x8 bfr[8];
#pragma unroll
    for (int ni = 0; ni < 8; ++ni) {
      int col = wc * 128 + ni * 16 + lr;
      bfr[ni] = *(const s16x8*)&Bs[col * 32 + ((g ^ (col & 3)) << 3)];
    }
#pragma unroll
    for (int mi = 0; mi < 4; ++mi) {
      int row = wr * 64 + mi * 16 + lr;
      int c1 = (2 * g) ^ (row & 7);
      int c2 = (2 * g + 1) ^ (row & 7);
      f32x4 a0 = *(const f32x4*)&As[row * 32 + c1 * 4];
      f32x4 a1 = *(const f32x4*)&As[row * 32 + c2 * 4];
      s16x8 af = __builtin_bit_cast(s16x8,
          (u32x4){cvtpk(a0[0], a0[1]), cvtpk(a0[2], a0[3]),
                  cvtpk(a1[0], a1[1]), cvtpk(a1[2], a1[3])});
#pragma unroll
      for (int ni = 0; ni < 8; ++ni)
        acc[mi][ni] = mfma16(af, bfr[ni], acc[mi][ni]);
    }
    __syncthreads();
  }
#pragma unroll
  for (int ni = 0; ni < 8; ++ni) {
    const int col = wc * 128 + ni * 16 + lr;
    const float bv = bias[col];
#pragma unroll
    for (int mi = 0; mi < 4; ++mi) {
      const int r0 = tM + wr * 64 + mi * 16 + g * 4;
      f32x4 c = acc[mi][ni];
#pragma unroll
      for (int j = 0; j < 4; ++j)
        XR[(size_t)(r0 + j) * 256 + col] = f2b(c[j] + bv);
    }
  }
}

// ---------------------------------------------------------------------------
// K2: QKV GEMM.  C[32768,768] = XR_bf16[32768,256] @ wqkvT^T + bqkv.
// grid (256, 3): y-strip 0 -> Q rows, 1 -> K rows, 2 -> V transposed.
// ---------------------------------------------------------------------------
__global__ __launch_bounds__(256, 2) void k_gemm_qkv2(
    const ushort* __restrict__ XR, const ushort* __restrict__ WT,
    const float* __restrict__ bias,
    ushort* __restrict__ Qo, ushort* __restrict__ Ko, ushort* __restrict__ VTo)
{
  __shared__ ushort As[128 * 32];
  __shared__ ushort Bs[256 * 32];
  const int tid = threadIdx.x;
  const int l = tid & 63, w = tid >> 6;
  const int wr = w >> 1, wc = w & 1;
  const int g = l >> 4, lr = l & 15;
  const int bx = blockIdx.x;
  const int xs = (bx & 7) * 32 + (bx >> 3);
  const int tM = xs * 128, tN = blockIdx.y * 256;
  f32x4 acc[4][8] = {};

  for (int kt = 0; kt < 8; ++kt) {
    const int k0 = kt * 32;
#pragma unroll
    for (int j = 0; j < 2; ++j) {  // A: 8 KB bf16 (128 rows, stride 256)
      int chunk = j * 256 + tid;
      int row = chunk >> 2, kc = chunk & 3;
      gload16(XR + (size_t)(tM + row) * 256 + k0 + ((kc ^ (row & 3)) << 3),
              (char*)As + (j * 256 + w * 64) * 16);
    }
#pragma unroll
    for (int j = 0; j < 4; ++j) {  // B: 16 KB bf16 (256 rows, stride 256)
      int chunk = j * 256 + tid;
      int row = chunk >> 2, kc = chunk & 3;
      gload16(WT + (size_t)(tN + row) * 256 + k0 + ((kc ^ (row & 3)) << 3),
              (char*)Bs + (j * 256 + w * 64) * 16);
    }
    __syncthreads();
    s16x8 afr[4], bfr[8];
#pragma unroll
    for (int ni = 0; ni < 8; ++ni) {
      int col = wc * 128 + ni * 16 + lr;
      bfr[ni] = *(const s16x8*)&Bs[col * 32 + ((g ^ (col & 3)) << 3)];
    }
#pragma unroll
    for (int mi = 0; mi < 4; ++mi) {
      int row = wr * 64 + mi * 16 + lr;
      afr[mi] = *(const s16x8*)&As[row * 32 + ((g ^ (row & 3)) << 3)];
    }
#pragma unroll
    for (int mi = 0; mi < 4; ++mi)
#pragma unroll
      for (int ni = 0; ni < 8; ++ni)
        acc[mi][ni] = mfma16(afr[mi], bfr[ni], acc[mi][ni]);
    __syncthreads();
  }
  const int strip = blockIdx.y;
#pragma unroll
  for (int ni = 0; ni < 8; ++ni) {
    const int cc = wc * 128 + ni * 16 + lr;       // 0..255 within strip
    const float bv = bias[tN + cc];
#pragma unroll
    for (int mi = 0; mi < 4; ++mi) {
      const int r0 = tM + wr * 64 + mi * 16 + g * 4;
      f32x4 c = acc[mi][ni];
      if (strip < 2) {
        ushort* dst = strip ? Ko : Qo;
#pragma unroll
        for (int j = 0; j < 4; ++j)
          dst[(size_t)(r0 + j) * 256 + cc] = f2b(c[j] + bv);
      } else {
        const int n = r0 >> 12, lrr = r0 & 4095;
        ushort4 pv;
        pv.x = f2b(c[0] + bv); pv.y = f2b(c[1] + bv);
        pv.z = f2b(c[2] + bv); pv.w = f2b(c[3] + bv);
        *(ushort4*)&VTo[(size_t)n * 256 * 4096 + (size_t)cc * 4096 + lrr] = pv;
      }
    }
  }
}

// ---------------------------------------------------------------------------
// K3: flash attention.  4 waves x 32 q-rows, KBLK=32 double-buffered (64 KiB
// LDS -> 2 blocks/CU).  Conflict-free LDS layouts; K staged in kperm order so
// PV B-fragments are lane-local (zero shuffles).  Tile loop unrolled x2 with
// STATIC buffer index.  2-way KV split + combine fused into gemm_out.
// LDS map (bytes): K0@0  K1@16384  V0@32768  V1@49152.
// Structural ceiling: 128 VGPR + 128 AGPR = 256 regs/wave = 2 waves/SIMD hard
// cap (R3/R7/R8 experiments); ~785 TF effective.
// ---------------------------------------------------------------------------
#define KSC 0.0901687369f  /* log2(e)/sqrt(256) */

template<int NSPLIT>
__global__ __launch_bounds__(256, 2) void k_flash(
    const ushort* __restrict__ Qg, const ushort* __restrict__ Kg,
    const ushort* __restrict__ VTg, ushort* __restrict__ Po, float* __restrict__ MLo)
{
  __shared__ ushort SB[32768];
  const int tid = threadIdx.x;
  const int l = tid & 63, w = tid >> 6;
  const int by = blockIdx.x & 7;                       // batch -> XCD
  const int rest = blockIdx.x >> 3;
  const int split = (NSPLIT == 2) ? (rest & 1) : 0;
  const int qt = (NSPLIT == 2) ? (rest >> 1) : rest;
  const int NT = (NSPLIT == 2) ? 64 : 128;
  const int kv0 = split * 2048;
  const int q0 = qt * 128 + w * 32;
  const int cl = l & 31, h = l >> 5;
  const size_t qrow = (size_t)by * 4096 + q0 + cl;

  s16x8 qf[16];
#pragma unroll
  for (int s = 0; s < 16; ++s)
    qf[s] = *(const s16x8*)&Qg[qrow * 256 + s * 16 + h * 8];

  f32x16 ot[8] = {};
  float m_run = -1e30f, l_run = 0.0f;   // l_run is a per-half partial sum

  // loop-invariant per-thread LDS byte offsets
  const char* SBc = (const char*)SB;
  const int tbK = h * 512 + cl * 16;    // K: (2s+h)*512 + cl*16 - s part is imm
  const int tbV = h * 4096 + cl * 16;   // V: ks*8192 + h*4096 + mf*512 + cl*16

  // strength-reduced global staging pointers (j-dependence folds into imm)
  const ushort* kg = Kg + ((size_t)by * 4096 + kv0) * 256
                   + kperm(tid & 31) * 256 + (tid >> 5) * 8;   // +8192/tile
  const ushort* vg = VTg + (size_t)by * 256 * 4096 + kv0
                   + (size_t)tid * 4096;                       // +32/tile

  auto stageK = [&](const ushort* p, int buf) {
#pragma unroll
    for (int j = 0; j < 4; ++j)
      gload16(p + j * 64, (char*)SB + buf * 16384 + j * 4096 + w * 1024);
  };
  auto stageV = [&](const ushort* p, int buf) {
#pragma unroll
    for (int j = 0; j < 4; ++j)
      gload16(p + j * 8, (char*)SB + 32768 + buf * 16384 + j * 4096 + w * 1024);
  };

  stageK(kg, 0); stageV(vg, 0);
  __syncthreads();

#define FLASH_TILE(BUF)                                                        \
  {                                                                            \
    f32x16 sa = {};                                                            \
    __builtin_amdgcn_s_setprio(1);                                             \
    _Pragma("unroll")                                                          \
    for (int s = 0; s < 16; ++s) {                                             \
      s16x8 a = *(const s16x8*)(SBc + (BUF) * 16384 + s * 1024 + tbK);         \
      sa = mfma32(a, qf[s], sa);                                               \
    }                                                                          \
    __builtin_amdgcn_s_setprio(0);                                             \
    float t0 = max3(sa[0], sa[1], sa[2]);                                      \
    float t1 = max3(sa[3], sa[4], sa[5]);                                      \
    float t2 = max3(sa[6], sa[7], sa[8]);                                      \
    float t3 = max3(sa[9], sa[10], sa[11]);                                    \
    float t4 = max3(sa[12], sa[13], sa[14]);                                   \
    float pmax = fmaxf(max3(t0, t1, t2), max3(t3, t4, sa[15]));                \
    pmax = fmaxf(pmax, __shfl_xor(pmax, 32));                                  \
    if (!__all(pmax <= m_run + 120.0f)) {                                      \
      float m_new = fmaxf(m_run, pmax);                                        \
      float corr = exp2f((m_run - m_new) * KSC);                               \
      l_run *= corr;                                                           \
      _Pragma("unroll")                                                        \
      for (int mf = 0; mf < 8; ++mf)                                           \
        _Pragma("unroll")                                                      \
        for (int i = 0; i < 16; ++i) ot[mf][i] *= corr;                        \
      m_run = m_new;                                                           \
    }                                                                          \
    const float mK = m_run * KSC;                                              \
    unsigned pk[4][2];                                                         \
    float lp = 0.0f;                                                           \
    _Pragma("unroll")                                                          \
    for (int gq = 0; gq < 4; ++gq) {                                           \
      float p0 = exp2f(__builtin_fmaf(sa[4 * gq + 0], KSC, -mK));              \
      float p1 = exp2f(__builtin_fmaf(sa[4 * gq + 1], KSC, -mK));              \
      float p2 = exp2f(__builtin_fmaf(sa[4 * gq + 2], KSC, -mK));              \
      float p3 = exp2f(__builtin_fmaf(sa[4 * gq + 3], KSC, -mK));              \
      lp += (p0 + p1) + (p2 + p3);                                             \
      pk[gq][0] = cvtpk(p0, p1);                                               \
      pk[gq][1] = cvtpk(p2, p3);                                               \
    }                                                                          \
    l_run += lp;                                                               \
    _Pragma("unroll")                                                          \
    for (int ks = 0; ks < 2; ++ks) {                                           \
      const s16x8 pf = __builtin_bit_cast(s16x8,                               \
          (u32x4){pk[2 * ks][0], pk[2 * ks][1],                                \
                  pk[2 * ks + 1][0], pk[2 * ks + 1][1]});                      \
      __builtin_amdgcn_s_setprio(1);                                           \
      _Pragma("unroll")                                                        \
      for (int mf = 0; mf < 8; ++mf) {                                         \
        s16x8 va = *(const s16x8*)(SBc + 32768 + (BUF) * 16384 +               \
                                   ks * 8192 + mf * 512 + tbV);                \
        ot[mf] = mfma32(va, pf, ot[mf]);                                       \
      }                                                                        \
      __builtin_amdgcn_s_setprio(0);                                           \
    }                                                                          \
    __syncthreads();                                                           \
  }

  for (int t = 0; t < NT; t += 2) {
    if (t + 1 < NT) { stageK(kg + 8192, 1); stageV(vg + 32, 1); }
    FLASH_TILE(0)
    if (t + 2 < NT) { stageK(kg + 16384, 0); stageV(vg + 64, 0); }
    FLASH_TILE(1)
    kg += 16384; vg += 64;
  }
#undef FLASH_TILE

  const float l_tot = l_run + __shfl_xor(l_run, 32);
  const float rl = 1.0f / l_tot;
  const size_t orow = (size_t)split * 32768 + qrow;
#pragma unroll
  for (int mf = 0; mf < 8; ++mf)
#pragma unroll
    for (int c = 0; c < 4; ++c) {
      const int d0 = mf * 32 + 8 * c + 4 * h;
      uint2 pv;
      pv.x = cvtpk(ot[mf][4 * c + 0] * rl, ot[mf][4 * c + 1] * rl);
      pv.y = cvtpk(ot[mf][4 * c + 2] * rl, ot[mf][4 * c + 3] * rl);
      *(uint2*)&Po[orow * 256 + d0] = pv;
    }
  if (NSPLIT == 2 && h == 0) {
    float2 ml; ml.x = m_run; ml.y = l_tot;
    *(float2*)&MLo[orow * 2] = ml;
  }
}

// ---------------------------------------------------------------------------
// K4: out projection with fused split-combine.
// OUT_f32[32768,1024] = combine(P0,P1;ML)_bf16[32768,256] @ WOT^T + b_o.
// bx XCD-swizzled: each XCD owns 32 consecutive M-tiles -> P rows (2+2 MB)
// stay L2-resident across the 4 N-strips.
// ---------------------------------------------------------------------------
template<int COMB>
__global__ __launch_bounds__(256, 2) void k_gemm_out(
    const ushort* __restrict__ P0, const float* __restrict__ ML,
    const ushort* __restrict__ WT,
    const float* __restrict__ bias, float* __restrict__ OUT)
{
  __shared__ ushort As[128 * 32];
  __shared__ ushort Bs[256 * 32];
  __shared__ float2 Wr[128];
  const int tid = threadIdx.x;
  const int l = tid & 63, w = tid >> 6;
  const int wr = w >> 1, wc = w & 1;
  const int g = l >> 4, lr = l & 15;
  const int bx = blockIdx.x;
  const int xs = (bx & 7) * 32 + (bx >> 3);        // XCD-aware (256 % 8 == 0)
  const int tM = xs * 128, tN = blockIdx.y * 256;
  f32x4 acc[4][8] = {};

  if (COMB) {
    if (tid < 128) {
      const int r = tM + tid;
      float2 ml0 = *(const float2*)&ML[(size_t)r * 2];
      float2 ml1 = *(const float2*)&ML[(size_t)(32768 + r) * 2];
      float m = fmaxf(ml0.x, ml1.x);
      float a0 = ml0.y * exp2f((ml0.x - m) * KSC);
      float a1 = ml1.y * exp2f((ml1.x - m) * KSC);
      float inv = 1.0f / (a0 + a1);
      float2 wv; wv.x = a0 * inv; wv.y = a1 * inv;
      Wr[tid] = wv;
    }
    __syncthreads();
  }

  for (int kt = 0; kt < 8; ++kt) {
    const int k0 = kt * 32;
    if (COMB) {
#pragma unroll
      for (int j = 0; j < 2; ++j) {  // A: merge both partials -> bf16 LDS
        int chunk = j * 256 + tid;
        int row = chunk >> 2, kc = chunk & 3;
        size_t src = (size_t)(tM + row) * 256 + k0 + ((kc ^ (row & 3)) << 3);
        s16x8 x0 = *(const s16x8*)&P0[src];
        s16x8 x1 = *(const s16x8*)&P0[src + (size_t)32768 * 256];
        float2 wv = Wr[row];
        u32x4 m;
#pragma unroll
        for (int p = 0; p < 4; ++p) {
          float lo = __builtin_fmaf(wv.y, b2f(x1[2 * p]),     wv.x * b2f(x0[2 * p]));
          float hi = __builtin_fmaf(wv.y, b2f(x1[2 * p + 1]), wv.x * b2f(x0[2 * p + 1]));
          m[p] = cvtpk(lo, hi);
        }
        *(s16x8*)((char*)As + chunk * 16) = __builtin_bit_cast(s16x8, m);
      }
    } else {
#pragma unroll
      for (int j = 0; j < 2; ++j) {  // A: 128x32 bf16 direct
        int chunk = j * 256 + tid;
        int row = chunk >> 2, kc = chunk & 3;
        gload16(P0 + (size_t)(tM + row) * 256 + k0 + ((kc ^ (row & 3)) << 3),
                (char*)As + (j * 256 + w * 64) * 16);
      }
    }
#pragma unroll
    for (int j = 0; j < 4; ++j) {  // B: 256x32 bf16
      int chunk = j * 256 + tid;
      int row = chunk >> 2, kc = chunk & 3;
      gload16(WT + (size_t)(tN + row) * 256 + k0 + ((kc ^ (row & 3)) << 3),
              (char*)Bs + (j * 256 + w * 64) * 16);
    }
    __syncthreads();
    s16x8 afr[4], bfr[8];
#pragma unroll
    for (int ni = 0; ni < 8; ++ni) {
      int col = wc * 128 + ni * 16 + lr;
      bfr[ni] = *(const s16x8*)&Bs[col * 32 + ((g ^ (col & 3)) << 3)];
    }
#pragma unroll
    for (int mi = 0; mi < 4; ++mi) {
      int row = wr * 64 + mi * 16 + lr;
      afr[mi] = *(const s16x8*)&As[row * 32 + ((g ^ (row & 3)) << 3)];
    }
#pragma unroll
    for (int mi = 0; mi < 4; ++mi)
#pragma unroll
      for (int ni = 0; ni < 8; ++ni)
        acc[mi][ni] = mfma16(afr[mi], bfr[ni], acc[mi][ni]);
    __syncthreads();
  }
#pragma unroll
  for (int ni = 0; ni < 8; ++ni) {
    const int col = tN + wc * 128 + ni * 16 + lr;
    const float bv = bias[col];
#pragma unroll
    for (int mi = 0; mi < 4; ++mi) {
      const int r0 = tM + wr * 64 + mi * 16 + g * 4;
      f32x4 c = acc[mi][ni];
#pragma unroll
      for (int j = 0; j < 4; ++j)
        OUT[(size_t)(r0 + j) * 1024 + col] = c[j] + bv;
    }
  }
}

// ---------------------------------------------------------------------------
extern "C" void kernel_launch(void* const* d_in, const int* in_sizes, int n_in,
                              void* d_out, int out_size, void* d_ws, size_t ws_size,
                              hipStream_t stream) {
  const float* x    = (const float*)d_in[0];
  const float* w_sr = (const float*)d_in[1];
  const float* b_sr = (const float*)d_in[2];
  const float* w_q  = (const float*)d_in[3];
  const float* b_q  = (const float*)d_in[4];
  const float* w_k  = (const float*)d_in[5];
  const float* b_k  = (const float*)d_in[6];
  const float* w_v  = (const float*)d_in[7];
  const float* b_v  = (const float*)d_in[8];
  const float* w_o  = (const float*)d_in[9];
  const float* b_o  = (const float*)d_in[10];
  float* out = (float*)d_out;

  char* ws = (char*)d_ws;
  const size_t MB = 1024 * 1024;
  const size_t KB = 1024;
  const bool split = ws_size >= 84 * MB;

  ushort* Q  = (ushort*)(ws);
  ushort* K  = (ushort*)(ws + 16 * MB);
  ushort* VT = (ushort*)(ws + 32 * MB);
  ushort* XR = (ushort*)(ws + 48 * MB);      // dead before flash writes P here
  ushort* P  = (ushort*)(ws + 48 * MB);      // [split0 | split1]
  float*  ML    = (float*) (ws + 80 * MB);
  char*   wbase = split ? (ws + 80 * MB + 512 * KB) : (ws + 64 * MB);
  ushort* WSRT  = (ushort*)(wbase);                  // 512 KB
  ushort* WQKVT = (ushort*)(wbase + 512 * KB);       // 384 KB
  ushort* WOT   = (ushort*)(wbase + 1024 * KB);      // 512 KB
  float*  BQKV  = (float*) (wbase + 1536 * KB);      // 3 KB

  k_prep<<<1024, 256, 0, stream>>>(w_sr, WSRT);
  k_gemm_sr<<<2049, 256, 0, stream>>>(x, WSRT, b_sr, XR,
                                      w_q, b_q, w_k, b_k, w_v, b_v, w_o,
                                      WQKVT, WOT, BQKV);
  k_gemm_qkv2<<<dim3(256, 3), 256, 0, stream>>>(XR, WQKVT, BQKV, Q, K, VT);
  if (split) {
    k_flash<2><<<512, 256, 0, stream>>>(Q, K, VT, P, ML);
    k_gemm_out<1><<<dim3(256, 4), 256, 0, stream>>>(P, ML, WOT, b_o, out);
  } else {
    k_flash<1><<<256, 256, 0, stream>>>(Q, K, VT, P, nullptr);
    k_gemm_out<0><<<dim3(256, 4), 256, 0, stream>>>(P, nullptr, WOT, b_o, out);
  }
}